// Round 1
// baseline (721.812 us; speedup 1.0000x reference)
//
#include <hip/hip_runtime.h>
#include <cstdint>
#include <cstddef>

// MultiHeadSelfAttention forward, MI355X/gfx950.
// Pipeline: [gemm_bt x3: Q,K,V bf16] -> [rope on Q,K] -> [flash attn] -> [gemm_bt: out fp32]
// All GEMMs: C = A * W^T with W stored (N x K) row-major (matches einsum 'bsi,oi->bso').
// bf16 MFMA 16x16x32, fp32 accumulate. Verified frag layouts per cdna_hip_programming.md §3:
//   C/D: row = (lane>>4)*4 + j, col = lane&15
//   A:   row = lane&15,        k = (lane>>4)*8 + j   (8 consecutive bf16 -> ds_read_b128)
//   B:   col = lane&15,        k = (lane>>4)*8 + j   (B^T stored row-major -> consecutive)

typedef __attribute__((ext_vector_type(8))) short bf16x8;
typedef __attribute__((ext_vector_type(4))) float f32x4;

#define LOG2E 1.4426950408889634f

__device__ __forceinline__ unsigned short f2bf(float f) {
  unsigned int u = __builtin_bit_cast(unsigned int, f);
  unsigned int r = (u + 0x7FFFu + ((u >> 16) & 1u)) >> 16;  // RNE
  return (unsigned short)r;
}
__device__ __forceinline__ float bf2f(unsigned short h) {
  return __builtin_bit_cast(float, (unsigned int)h << 16);
}
__device__ __forceinline__ unsigned int packbf2(float a, float b) {
  return (unsigned int)f2bf(a) | ((unsigned int)f2bf(b) << 16);
}

// C[M,N] = A[M,K] * W[N,K]^T.  A: fp32 or bf16(ushort). W: fp32. C: fp32 or bf16.
// 128x128 tile, BK=64, 256 threads (4 waves, 2x2), register staging w/ inline f32->bf16.
template <bool A_F32, bool C_F32>
__global__ __launch_bounds__(256) void gemm_bt(const void* __restrict__ Ap,
                                               const float* __restrict__ Wp,
                                               void* __restrict__ Cp,
                                               int M, int N, int K) {
  __shared__ alignas(16) unsigned short As[128 * 64];
  __shared__ alignas(16) unsigned short Bs[128 * 64];
  const int t = threadIdx.x;
  const int lane = t & 63;
  const int w = t >> 6;
  const int wr = w >> 1, wc = w & 1;
  const int fr = lane & 15, fq = lane >> 4;
  const int m0 = blockIdx.x * 128, n0 = blockIdx.y * 128;

  const f32x4 zero = {0.f, 0.f, 0.f, 0.f};
  f32x4 acc[4][4];
#pragma unroll
  for (int m = 0; m < 4; ++m)
#pragma unroll
    for (int n = 0; n < 4; ++n) acc[m][n] = zero;

  for (int k0 = 0; k0 < K; k0 += 64) {
    // ---- stage A tile (128x64) and B tile (128x64) into LDS as bf16 ----
#pragma unroll
    for (int it = 0; it < 4; ++it) {
      int flat = it * 2048 + t * 8;          // element index in [128][64] tile
      int row = flat >> 6, col = flat & 63;
      if constexpr (A_F32) {
        const float* g = (const float*)Ap + (size_t)(m0 + row) * K + (k0 + col);
        float4 u0 = *(const float4*)g;
        float4 u1 = *(const float4*)(g + 4);
        uint4 v = {packbf2(u0.x, u0.y), packbf2(u0.z, u0.w),
                   packbf2(u1.x, u1.y), packbf2(u1.z, u1.w)};
        *(uint4*)&As[flat] = v;
      } else {
        const unsigned short* g = (const unsigned short*)Ap + (size_t)(m0 + row) * K + (k0 + col);
        *(uint4*)&As[flat] = *(const uint4*)g;
      }
      {
        const float* g = Wp + (size_t)(n0 + row) * K + (k0 + col);
        float4 u0 = *(const float4*)g;
        float4 u1 = *(const float4*)(g + 4);
        uint4 v = {packbf2(u0.x, u0.y), packbf2(u0.z, u0.w),
                   packbf2(u1.x, u1.y), packbf2(u1.z, u1.w)};
        *(uint4*)&Bs[flat] = v;
      }
    }
    __syncthreads();
    // ---- MFMA inner loop ----
#pragma unroll
    for (int kk = 0; kk < 2; ++kk) {
      bf16x8 a[4], b[4];
#pragma unroll
      for (int m = 0; m < 4; ++m)
        a[m] = *(const bf16x8*)&As[(wr * 64 + m * 16 + fr) * 64 + kk * 32 + fq * 8];
#pragma unroll
      for (int n = 0; n < 4; ++n)
        b[n] = *(const bf16x8*)&Bs[(wc * 64 + n * 16 + fr) * 64 + kk * 32 + fq * 8];
#pragma unroll
      for (int m = 0; m < 4; ++m)
#pragma unroll
        for (int n = 0; n < 4; ++n)
          acc[m][n] = __builtin_amdgcn_mfma_f32_16x16x32_bf16(a[m], b[n], acc[m][n], 0, 0, 0);
    }
    __syncthreads();
  }

  // ---- epilogue ----
#pragma unroll
  for (int m = 0; m < 4; ++m)
#pragma unroll
    for (int n = 0; n < 4; ++n)
#pragma unroll
      for (int j = 0; j < 4; ++j) {
        int row = m0 + wr * 64 + m * 16 + fq * 4 + j;
        int col = n0 + wc * 64 + n * 16 + fr;
        float v = acc[m][n][j];
        if constexpr (C_F32)
          ((float*)Cp)[(size_t)row * N + col] = v;
        else
          ((unsigned short*)Cp)[(size_t)row * N + col] = f2bf(v);
      }
}

// RoPE in-place on Q (blockIdx.y==0) and K (==1), bf16 buffers of shape (8192, 1024).
// Pair p within head: angle = pos * theta^(-p/32); (x1,x2)=(c[2p],c[2p+1]) rotated.
__global__ void rope_kernel(unsigned short* __restrict__ Q,
                            unsigned short* __restrict__ Kb,
                            const int* __restrict__ tp) {
  int idx = blockIdx.x * 256 + threadIdx.x;     // 8192*512 pairs
  unsigned short* ptr = blockIdx.y ? Kb : Q;
  int r = idx >> 9;        // row in (B*S)
  int pc = idx & 511;      // h*32 + i
  int i = pc & 31;
  int s = r & 2047;        // seq position
  float pos = (float)tp[s];
  float inv = exp2f((float)i * (-13.287712379549449f / 32.0f));  // theta^(-i/32)
  float ang = pos * inv;
  float sn, cs;
  sincosf(ang, &sn, &cs);
  size_t off = (size_t)r * 1024 + pc * 2;
  unsigned int v = *(const unsigned int*)&ptr[off];
  float x1 = bf2f((unsigned short)(v & 0xFFFFu));
  float x2 = bf2f((unsigned short)(v >> 16));
  *(unsigned int*)&ptr[off] = packbf2(x1 * cs - x2 * sn, x1 * sn + x2 * cs);
}

// Flash attention, causal. One block per (b, h, 64-row Q tile). 4 waves x 16 Q rows.
// Q,K,V,O are bf16 (8192, 1024) matrices; head h occupies cols [h*64, h*64+64).
__global__ __launch_bounds__(256) void attn_kernel(const unsigned short* __restrict__ Q,
                                                   const unsigned short* __restrict__ K,
                                                   const unsigned short* __restrict__ V,
                                                   unsigned short* __restrict__ O) {
  __shared__ alignas(16) unsigned short Ks[64 * 64];
  __shared__ alignas(16) unsigned short Vt[64 * 64];   // transposed: [dk][kv]
  __shared__ alignas(16) unsigned short Pl[4][16 * 64];
  const int t = threadIdx.x;
  const int lane = t & 63, w = t >> 6;
  const int fr = lane & 15, fq = lane >> 4;
  const int q0 = blockIdx.x * 64;
  const int h = blockIdx.y, b = blockIdx.z;
  const size_t base = ((size_t)b * 2048) * 1024 + (size_t)h * 64;

  // stage Q tile through Ks buffer, hoist frags to registers
#pragma unroll
  for (int it = 0; it < 2; ++it) {
    int flat = it * 2048 + t * 8;
    int row = flat >> 6, col = flat & 63;
    *(uint4*)&Ks[flat] = *(const uint4*)&Q[base + (size_t)(q0 + row) * 1024 + col];
  }
  __syncthreads();
  bf16x8 qf[2];
#pragma unroll
  for (int kk = 0; kk < 2; ++kk)
    qf[kk] = *(const bf16x8*)&Ks[(w * 16 + fr) * 64 + kk * 32 + fq * 8];

  float m_[4] = {-INFINITY, -INFINITY, -INFINITY, -INFINITY};
  float l_[4] = {0.f, 0.f, 0.f, 0.f};
  const f32x4 zero = {0.f, 0.f, 0.f, 0.f};
  f32x4 oacc[4];
#pragma unroll
  for (int n = 0; n < 4; ++n) oacc[n] = zero;

  for (int kv0 = 0; kv0 <= q0; kv0 += 64) {
    __syncthreads();  // previous iteration's PV reads done before restaging
    // ---- stage K (row-major) and V (transposed) ----
#pragma unroll
    for (int it = 0; it < 2; ++it) {
      int flat = it * 2048 + t * 8;
      int row = flat >> 6, col = flat & 63;
      *(uint4*)&Ks[flat] = *(const uint4*)&K[base + (size_t)(kv0 + row) * 1024 + col];
      union { uint4 v; unsigned short u[8]; } uu;
      uu.v = *(const uint4*)&V[base + (size_t)(kv0 + row) * 1024 + col];
#pragma unroll
      for (int e = 0; e < 8; ++e) Vt[(col + e) * 64 + row] = uu.u[e];
    }
    __syncthreads();

    // ---- S = Q K^T (per wave: 16 q-rows x 64 kv) ----
    f32x4 sa[4];
#pragma unroll
    for (int n = 0; n < 4; ++n) sa[n] = zero;
#pragma unroll
    for (int kk = 0; kk < 2; ++kk) {
#pragma unroll
      for (int n = 0; n < 4; ++n) {
        bf16x8 kf = *(const bf16x8*)&Ks[(n * 16 + fr) * 64 + kk * 32 + fq * 8];
        sa[n] = __builtin_amdgcn_mfma_f32_16x16x32_bf16(qf[kk], kf, sa[n], 0, 0, 0);
      }
    }

    // ---- online softmax (rows spread: lane holds rows fq*4+j, cols n*16+fr) ----
    const bool diag = (kv0 == q0);
    float sc[4][4], rmax[4];
#pragma unroll
    for (int j = 0; j < 4; ++j) rmax[j] = -3.0e38f;
#pragma unroll
    for (int n = 0; n < 4; ++n)
#pragma unroll
      for (int j = 0; j < 4; ++j) {
        float s = sa[n][j] * 0.125f;  // 1/sqrt(64)
        if (diag && (n * 16 + fr > w * 16 + fq * 4 + j)) s = -3.0e38f;
        sc[n][j] = s;
        rmax[j] = fmaxf(rmax[j], s);
      }
#pragma unroll
    for (int msk = 1; msk < 16; msk <<= 1)
#pragma unroll
      for (int j = 0; j < 4; ++j) rmax[j] = fmaxf(rmax[j], __shfl_xor(rmax[j], msk));

    float alpha[4], psum[4];
#pragma unroll
    for (int j = 0; j < 4; ++j) {
      float mn = fmaxf(m_[j], rmax[j]);
      alpha[j] = exp2f((m_[j] - mn) * LOG2E);
      m_[j] = mn;
      psum[j] = 0.f;
    }
#pragma unroll
    for (int n = 0; n < 4; ++n)
#pragma unroll
      for (int j = 0; j < 4; ++j) {
        float p = exp2f((sc[n][j] - m_[j]) * LOG2E);
        psum[j] += p;
        Pl[w][(fq * 4 + j) * 64 + n * 16 + fr] = f2bf(p);
      }
#pragma unroll
    for (int msk = 1; msk < 16; msk <<= 1)
#pragma unroll
      for (int j = 0; j < 4; ++j) psum[j] += __shfl_xor(psum[j], msk);
#pragma unroll
    for (int j = 0; j < 4; ++j) l_[j] = l_[j] * alpha[j] + psum[j];
#pragma unroll
    for (int n = 0; n < 4; ++n)
#pragma unroll
      for (int j = 0; j < 4; ++j) oacc[n][j] = oacc[n][j] * alpha[j];

    __syncthreads();  // P visible (cross-lane), LDS writes drained

    // ---- O += P V ----
#pragma unroll
    for (int kk = 0; kk < 2; ++kk) {
      bf16x8 pf = *(const bf16x8*)&Pl[w][fr * 64 + kk * 32 + fq * 8];
#pragma unroll
      for (int n = 0; n < 4; ++n) {
        bf16x8 vf = *(const bf16x8*)&Vt[(n * 16 + fr) * 64 + kk * 32 + fq * 8];
        oacc[n] = __builtin_amdgcn_mfma_f32_16x16x32_bf16(pf, vf, oacc[n], 0, 0, 0);
      }
    }
  }

  // ---- epilogue: normalize and store bf16 ----
#pragma unroll
  for (int n = 0; n < 4; ++n)
#pragma unroll
    for (int j = 0; j < 4; ++j) {
      float o = oacc[n][j] / l_[j];
      size_t row = (size_t)(q0 + w * 16 + fq * 4 + j);
      O[base + row * 1024 + n * 16 + fr] = f2bf(o);
    }
}

extern "C" void kernel_launch(void* const* d_in, const int* in_sizes, int n_in,
                              void* d_out, int out_size, void* d_ws, size_t ws_size,
                              hipStream_t stream) {
  const float* x  = (const float*)d_in[0];
  const int* tp   = (const int*)d_in[1];
  const float* Wq = (const float*)d_in[2];
  const float* Wk = (const float*)d_in[3];
  const float* Wv = (const float*)d_in[4];
  const float* Wo = (const float*)d_in[5];
  float* out = (float*)d_out;

  const size_t MAT = (size_t)8192 * 1024;  // elements per (B*S, D) bf16 matrix
  unsigned short* Qb = (unsigned short*)d_ws;
  unsigned short* Kb = Qb + MAT;
  unsigned short* Vb = Kb + MAT;
  unsigned short* Ob = Vb + MAT;

  dim3 gg(64, 8);  // M/128, N/128
  gemm_bt<true, false><<<gg, 256, 0, stream>>>((const void*)x, Wq, (void*)Qb, 8192, 1024, 1024);
  gemm_bt<true, false><<<gg, 256, 0, stream>>>((const void*)x, Wk, (void*)Kb, 8192, 1024, 1024);
  gemm_bt<true, false><<<gg, 256, 0, stream>>>((const void*)x, Wv, (void*)Vb, 8192, 1024, 1024);
  rope_kernel<<<dim3(16384, 2), 256, 0, stream>>>(Qb, Kb, tp);
  attn_kernel<<<dim3(32, 16, 4), 256, 0, stream>>>(Qb, Kb, Vb, Ob);
  gemm_bt<false, true><<<gg, 256, 0, stream>>>((const void*)Ob, Wo, (void*)out, 8192, 1024, 1024);
}

// Round 2
// 569.668 us; speedup vs baseline: 1.2671x; 1.2671x over previous
//
#include <hip/hip_runtime.h>
#include <cstdint>
#include <cstddef>

// MultiHeadSelfAttention forward, MI355X/gfx950.
// Round 2: XOR-swizzled LDS everywhere (kill 128B-row-stride bank conflicts);
// V GEMM writes V^T (B,H,d_k,S) so attention never transposes in LDS.
//
// Frag layouts (verified, cdna_hip_programming.md §3, mfma_f32_16x16x32_bf16):
//   C/D: row = (lane>>4)*4 + j, col = lane&15
//   A:   row = lane&15,        k = (lane>>4)*8 + j
//   B:   col = lane&15,        k = (lane>>4)*8 + j

typedef __attribute__((ext_vector_type(8))) short bf16x8;
typedef __attribute__((ext_vector_type(4))) float f32x4;

#define LOG2E 1.4426950408889634f

__device__ __forceinline__ unsigned short f2bf(float f) {
  unsigned int u = __builtin_bit_cast(unsigned int, f);
  unsigned int r = (u + 0x7FFFu + ((u >> 16) & 1u)) >> 16;  // RNE
  return (unsigned short)r;
}
__device__ __forceinline__ float bf2f(unsigned short h) {
  return __builtin_bit_cast(float, (unsigned int)h << 16);
}
__device__ __forceinline__ unsigned int packbf2(float a, float b) {
  return (unsigned int)f2bf(a) | ((unsigned int)f2bf(b) << 16);
}
// XOR swizzle for [R][64]-ushort row-major LDS tiles: byte ^= ((row&7)<<4).
// In ushort units: flip bits 3..5 by row&7. Preserves 16B alignment.
__device__ __forceinline__ int swz(int idx) {
  return idx ^ (((idx >> 6) & 7) << 3);
}

// C[M,N] = A[M,K] * W[N,K]^T.  A: fp32 or bf16(ushort). W: fp32.
// OUT_MODE: 0 = fp32 C row-major; 1 = bf16 C row-major; 2 = bf16 V^T (B,H,64,2048).
// 128x128 tile, BK=64, 256 threads (4 waves, 2x2).
template <bool A_F32, int OUT_MODE>
__global__ __launch_bounds__(256) void gemm_bt(const void* __restrict__ Ap,
                                               const float* __restrict__ Wp,
                                               void* __restrict__ Cp,
                                               int M, int N, int K) {
  __shared__ alignas(16) unsigned short As[128 * 64];
  __shared__ alignas(16) unsigned short Bs[128 * 64];
  const int t = threadIdx.x;
  const int lane = t & 63;
  const int w = t >> 6;
  const int wr = w >> 1, wc = w & 1;
  const int fr = lane & 15, fq = lane >> 4;
  const int m0 = blockIdx.x * 128, n0 = blockIdx.y * 128;

  const f32x4 zero = {0.f, 0.f, 0.f, 0.f};
  f32x4 acc[4][4];
#pragma unroll
  for (int m = 0; m < 4; ++m)
#pragma unroll
    for (int n = 0; n < 4; ++n) acc[m][n] = zero;

  for (int k0 = 0; k0 < K; k0 += 64) {
#pragma unroll
    for (int it = 0; it < 4; ++it) {
      int flat = it * 2048 + t * 8;          // element index in [128][64] tile
      int row = flat >> 6, col = flat & 63;
      if constexpr (A_F32) {
        const float* g = (const float*)Ap + (size_t)(m0 + row) * K + (k0 + col);
        float4 u0 = *(const float4*)g;
        float4 u1 = *(const float4*)(g + 4);
        uint4 v = {packbf2(u0.x, u0.y), packbf2(u0.z, u0.w),
                   packbf2(u1.x, u1.y), packbf2(u1.z, u1.w)};
        *(uint4*)&As[swz(flat)] = v;
      } else {
        const unsigned short* g = (const unsigned short*)Ap + (size_t)(m0 + row) * K + (k0 + col);
        *(uint4*)&As[swz(flat)] = *(const uint4*)g;
      }
      {
        const float* g = Wp + (size_t)(n0 + row) * K + (k0 + col);
        float4 u0 = *(const float4*)g;
        float4 u1 = *(const float4*)(g + 4);
        uint4 v = {packbf2(u0.x, u0.y), packbf2(u0.z, u0.w),
                   packbf2(u1.x, u1.y), packbf2(u1.z, u1.w)};
        *(uint4*)&Bs[swz(flat)] = v;
      }
    }
    __syncthreads();
#pragma unroll
    for (int kk = 0; kk < 2; ++kk) {
      bf16x8 a[4], b[4];
#pragma unroll
      for (int m = 0; m < 4; ++m)
        a[m] = *(const bf16x8*)&As[swz((wr * 64 + m * 16 + fr) * 64 + kk * 32 + fq * 8)];
#pragma unroll
      for (int n = 0; n < 4; ++n)
        b[n] = *(const bf16x8*)&Bs[swz((wc * 64 + n * 16 + fr) * 64 + kk * 32 + fq * 8)];
#pragma unroll
      for (int m = 0; m < 4; ++m)
#pragma unroll
        for (int n = 0; n < 4; ++n)
          acc[m][n] = __builtin_amdgcn_mfma_f32_16x16x32_bf16(a[m], b[n], acc[m][n], 0, 0, 0);
    }
    __syncthreads();
  }

  // ---- epilogue ----
#pragma unroll
  for (int m = 0; m < 4; ++m)
#pragma unroll
    for (int n = 0; n < 4; ++n) {
      int row = m0 + wr * 64 + m * 16 + fq * 4;  // j = 0..3 consecutive rows
      int col = n0 + wc * 64 + n * 16 + fr;
      if constexpr (OUT_MODE == 0) {
#pragma unroll
        for (int j = 0; j < 4; ++j)
          ((float*)Cp)[(size_t)(row + j) * N + col] = acc[m][n][j];
      } else if constexpr (OUT_MODE == 1) {
#pragma unroll
        for (int j = 0; j < 4; ++j)
          ((unsigned short*)Cp)[(size_t)(row + j) * N + col] = f2bf(acc[m][n][j]);
      } else {
        // V^T layout: (B, H, d_k=64, S=2048), s contiguous. 4 consecutive s per lane.
        int b = row >> 11, s = row & 2047;
        int h = col >> 6, d = col & 63;
        ushort4 v4 = {f2bf(acc[m][n][0]), f2bf(acc[m][n][1]),
                      f2bf(acc[m][n][2]), f2bf(acc[m][n][3])};
        *(ushort4*)&((unsigned short*)Cp)[(((size_t)b * 16 + h) * 64 + d) * 2048 + s] = v4;
      }
    }
}

// RoPE in-place on Q (blockIdx.y==0) and K (==1), bf16 buffers of shape (8192, 1024).
__global__ void rope_kernel(unsigned short* __restrict__ Q,
                            unsigned short* __restrict__ Kb,
                            const int* __restrict__ tp) {
  int idx = blockIdx.x * 256 + threadIdx.x;     // 8192*512 pairs
  unsigned short* ptr = blockIdx.y ? Kb : Q;
  int r = idx >> 9;        // row in (B*S)
  int pc = idx & 511;      // h*32 + i
  int i = pc & 31;
  int s = r & 2047;        // seq position
  float pos = (float)tp[s];
  float inv = exp2f((float)i * (-13.287712379549449f / 32.0f));  // theta^(-i/32)
  float ang = pos * inv;
  float sn, cs;
  sincosf(ang, &sn, &cs);
  size_t off = (size_t)r * 1024 + pc * 2;
  unsigned int v = *(const unsigned int*)&ptr[off];
  float x1 = bf2f((unsigned short)(v & 0xFFFFu));
  float x2 = bf2f((unsigned short)(v >> 16));
  *(unsigned int*)&ptr[off] = packbf2(x1 * cs - x2 * sn, x1 * sn + x2 * cs);
}

// Flash attention, causal. One block per (b, h, 64-row Q tile). 4 waves x 16 Q rows.
// Q,K bf16 (8192,1024); V^T bf16 (B,H,64,2048); O bf16 (8192,1024).
__global__ __launch_bounds__(256) void attn_kernel(const unsigned short* __restrict__ Q,
                                                   const unsigned short* __restrict__ K,
                                                   const unsigned short* __restrict__ Vt_g,
                                                   unsigned short* __restrict__ O) {
  __shared__ alignas(16) unsigned short Ks[64 * 64];
  __shared__ alignas(16) unsigned short Vt[64 * 64];   // [d][kv], from V^T global
  __shared__ alignas(16) unsigned short Pl[4][16 * 64];
  const int t = threadIdx.x;
  const int lane = t & 63, w = t >> 6;
  const int fr = lane & 15, fq = lane >> 4;
  const int q0 = blockIdx.x * 64;
  const int h = blockIdx.y, b = blockIdx.z;
  const size_t base = ((size_t)b * 2048) * 1024 + (size_t)h * 64;
  const size_t vbase = ((size_t)b * 16 + h) * 64 * 2048;

  // stage Q tile through Ks buffer (swizzled), hoist frags to registers
#pragma unroll
  for (int it = 0; it < 2; ++it) {
    int flat = it * 2048 + t * 8;
    int row = flat >> 6, col = flat & 63;
    *(uint4*)&Ks[swz(flat)] = *(const uint4*)&Q[base + (size_t)(q0 + row) * 1024 + col];
  }
  __syncthreads();
  bf16x8 qf[2];
#pragma unroll
  for (int kk = 0; kk < 2; ++kk)
    qf[kk] = *(const bf16x8*)&Ks[swz((w * 16 + fr) * 64 + kk * 32 + fq * 8)];

  float m_[4] = {-INFINITY, -INFINITY, -INFINITY, -INFINITY};
  float l_[4] = {0.f, 0.f, 0.f, 0.f};
  const f32x4 zero = {0.f, 0.f, 0.f, 0.f};
  f32x4 oacc[4];
#pragma unroll
  for (int n = 0; n < 4; ++n) oacc[n] = zero;

  for (int kv0 = 0; kv0 <= q0; kv0 += 64) {
    __syncthreads();  // previous tile's LDS reads done before restaging
    // ---- stage K (row-major from K) and V^T (row-major from Vt_g), swizzled ----
#pragma unroll
    for (int it = 0; it < 2; ++it) {
      int flat = it * 2048 + t * 8;
      int row = flat >> 6, col = flat & 63;
      *(uint4*)&Ks[swz(flat)] = *(const uint4*)&K[base + (size_t)(kv0 + row) * 1024 + col];
      *(uint4*)&Vt[swz(flat)] = *(const uint4*)&Vt_g[vbase + (size_t)row * 2048 + kv0 + col];
    }
    __syncthreads();

    // ---- S = Q K^T (per wave: 16 q-rows x 64 kv) ----
    f32x4 sa[4];
#pragma unroll
    for (int n = 0; n < 4; ++n) sa[n] = zero;
#pragma unroll
    for (int kk = 0; kk < 2; ++kk) {
#pragma unroll
      for (int n = 0; n < 4; ++n) {
        bf16x8 kf = *(const bf16x8*)&Ks[swz((n * 16 + fr) * 64 + kk * 32 + fq * 8)];
        sa[n] = __builtin_amdgcn_mfma_f32_16x16x32_bf16(qf[kk], kf, sa[n], 0, 0, 0);
      }
    }

    // ---- online softmax (lane holds rows fq*4+j, cols n*16+fr) ----
    const bool diag = (kv0 == q0);
    float sc[4][4], rmax[4];
#pragma unroll
    for (int j = 0; j < 4; ++j) rmax[j] = -3.0e38f;
#pragma unroll
    for (int n = 0; n < 4; ++n)
#pragma unroll
      for (int j = 0; j < 4; ++j) {
        float s = sa[n][j] * 0.125f;  // 1/sqrt(64)
        if (diag && (n * 16 + fr > w * 16 + fq * 4 + j)) s = -3.0e38f;
        sc[n][j] = s;
        rmax[j] = fmaxf(rmax[j], s);
      }
#pragma unroll
    for (int msk = 1; msk < 16; msk <<= 1)
#pragma unroll
      for (int j = 0; j < 4; ++j) rmax[j] = fmaxf(rmax[j], __shfl_xor(rmax[j], msk));

    float alpha[4], psum[4];
#pragma unroll
    for (int j = 0; j < 4; ++j) {
      float mn = fmaxf(m_[j], rmax[j]);
      alpha[j] = exp2f((m_[j] - mn) * LOG2E);
      m_[j] = mn;
      psum[j] = 0.f;
    }
#pragma unroll
    for (int n = 0; n < 4; ++n)
#pragma unroll
      for (int j = 0; j < 4; ++j) {
        float p = exp2f((sc[n][j] - m_[j]) * LOG2E);
        psum[j] += p;
        Pl[w][swz((fq * 4 + j) * 64 + n * 16 + fr)] = f2bf(p);
      }
#pragma unroll
    for (int msk = 1; msk < 16; msk <<= 1)
#pragma unroll
      for (int j = 0; j < 4; ++j) psum[j] += __shfl_xor(psum[j], msk);
#pragma unroll
    for (int j = 0; j < 4; ++j) l_[j] = l_[j] * alpha[j] + psum[j];
#pragma unroll
    for (int n = 0; n < 4; ++n)
#pragma unroll
      for (int j = 0; j < 4; ++j) oacc[n][j] = oacc[n][j] * alpha[j];

    __syncthreads();  // P visible within wave's LDS region (drain lgkm), V/K ready

    // ---- O += P V ----
#pragma unroll
    for (int kk = 0; kk < 2; ++kk) {
      bf16x8 pf = *(const bf16x8*)&Pl[w][swz(fr * 64 + kk * 32 + fq * 8)];
#pragma unroll
      for (int n = 0; n < 4; ++n) {
        bf16x8 vf = *(const bf16x8*)&Vt[swz((n * 16 + fr) * 64 + kk * 32 + fq * 8)];
        oacc[n] = __builtin_amdgcn_mfma_f32_16x16x32_bf16(pf, vf, oacc[n], 0, 0, 0);
      }
    }
  }

  // ---- epilogue: normalize and store bf16 ----
#pragma unroll
  for (int n = 0; n < 4; ++n)
#pragma unroll
    for (int j = 0; j < 4; ++j) {
      float o = oacc[n][j] / l_[j];
      size_t row = (size_t)(q0 + w * 16 + fq * 4 + j);
      O[base + row * 1024 + n * 16 + fr] = f2bf(o);
    }
}

extern "C" void kernel_launch(void* const* d_in, const int* in_sizes, int n_in,
                              void* d_out, int out_size, void* d_ws, size_t ws_size,
                              hipStream_t stream) {
  const float* x  = (const float*)d_in[0];
  const int* tp   = (const int*)d_in[1];
  const float* Wq = (const float*)d_in[2];
  const float* Wk = (const float*)d_in[3];
  const float* Wv = (const float*)d_in[4];
  const float* Wo = (const float*)d_in[5];
  float* out = (float*)d_out;

  const size_t MAT = (size_t)8192 * 1024;  // elements per bf16 matrix
  unsigned short* Qb  = (unsigned short*)d_ws;
  unsigned short* Kb  = Qb + MAT;
  unsigned short* Vtb = Kb + MAT;          // V^T (B,H,64,2048)
  unsigned short* Ob  = Vtb + MAT;

  dim3 gg(64, 8);  // M/128, N/128
  gemm_bt<true, 1><<<gg, 256, 0, stream>>>((const void*)x, Wq, (void*)Qb, 8192, 1024, 1024);
  gemm_bt<true, 1><<<gg, 256, 0, stream>>>((const void*)x, Wk, (void*)Kb, 8192, 1024, 1024);
  gemm_bt<true, 2><<<gg, 256, 0, stream>>>((const void*)x, Wv, (void*)Vtb, 8192, 1024, 1024);
  rope_kernel<<<dim3(16384, 2), 256, 0, stream>>>(Qb, Kb, tp);
  attn_kernel<<<dim3(32, 16, 4), 256, 0, stream>>>(Qb, Kb, Vtb, Ob);
  gemm_bt<false, 0><<<gg, 256, 0, stream>>>((const void*)Ob, Wo, (void*)out, 8192, 1024, 1024);
}

// Round 3
// 458.315 us; speedup vs baseline: 1.5749x; 1.2430x over previous
//
#include <hip/hip_runtime.h>
#include <cstdint>
#include <cstddef>

// MultiHeadSelfAttention forward, MI355X/gfx950.  Round 3.
//  - GEMMs: A-side bf16 via global_load_lds (16B, linear LDS), B-side fp32->bf16
//    reg-staged into XOR-swizzled LDS. 128x128 tile, BK=64, 4 waves.
//  - attn: paired q-tiles (x, 31-x) for perfect balance + full residency,
//    2 barriers/KV-tile, T14 register prefetch of next K/V tile.
//  - RoPE folds the 1/sqrt(d_k) scale into Q.
//
// Frag layouts (verified, mfma_f32_16x16x32_bf16):
//   C/D: row = (lane>>4)*4 + j, col = lane&15
//   A:   row = lane&15,        k = (lane>>4)*8 + j
//   B:   col = lane&15,        k = (lane>>4)*8 + j

typedef __attribute__((ext_vector_type(8))) short bf16x8;
typedef __attribute__((ext_vector_type(4))) float f32x4;

#define LOG2E 1.4426950408889634f

__device__ __forceinline__ unsigned short f2bf(float f) {
  unsigned int u = __builtin_bit_cast(unsigned int, f);
  unsigned int r = (u + 0x7FFFu + ((u >> 16) & 1u)) >> 16;  // RNE
  return (unsigned short)r;
}
__device__ __forceinline__ float bf2f(unsigned short h) {
  return __builtin_bit_cast(float, (unsigned int)h << 16);
}
__device__ __forceinline__ unsigned int packbf2(float a, float b) {
  return (unsigned int)f2bf(a) | ((unsigned int)f2bf(b) << 16);
}
// XOR swizzle for [R][64]-ushort row-major LDS tiles: byte ^= ((row&7)<<4).
__device__ __forceinline__ int swz(int idx) {
  return idx ^ (((idx >> 6) & 7) << 3);
}

// ---------------- fp32 -> bf16 bulk convert (8 elems/thread) ----------------
__global__ __launch_bounds__(256) void cvt_kernel(const float* __restrict__ in,
                                                  unsigned short* __restrict__ out,
                                                  int n8) {
  int i = blockIdx.x * 256 + threadIdx.x;
  if (i < n8) {
    float4 u0 = ((const float4*)in)[i * 2];
    float4 u1 = ((const float4*)in)[i * 2 + 1];
    uint4 v = {packbf2(u0.x, u0.y), packbf2(u0.z, u0.w),
               packbf2(u1.x, u1.y), packbf2(u1.z, u1.w)};
    ((uint4*)out)[i] = v;
  }
}

// ---------------- GEMM: C[M,N] = A[M,K](bf16) * W[N,K]^T(fp32) ----------------
// OUT_MODE: 0 = fp32 row-major; 1 = bf16 row-major; 2 = bf16 V^T (B,H,64,2048).
template <int OUT_MODE>
__global__ __launch_bounds__(256) void gemm_bt(const unsigned short* __restrict__ Ap,
                                               const float* __restrict__ Wp,
                                               void* __restrict__ Cp,
                                               int M, int N, int K) {
  __shared__ alignas(16) unsigned short As[128 * 64];  // linear (glds dest)
  __shared__ alignas(16) unsigned short Bs[128 * 64];  // swizzled
  const int t = threadIdx.x;
  const int lane = t & 63;
  const int w = t >> 6;
  const int wr = w >> 1, wc = w & 1;
  const int fr = lane & 15, fq = lane >> 4;
  const int m0 = blockIdx.x * 128, n0 = blockIdx.y * 128;

  const f32x4 zero = {0.f, 0.f, 0.f, 0.f};
  f32x4 acc[4][4];
#pragma unroll
  for (int m = 0; m < 4; ++m)
#pragma unroll
    for (int n = 0; n < 4; ++n) acc[m][n] = zero;

  for (int k0 = 0; k0 < K; k0 += 64) {
    // ---- A tile: async global->LDS, 16B/lane; chunk c = 8 rows of [128][64] ----
#pragma unroll
    for (int cc = 0; cc < 4; ++cc) {
      int c = w * 4 + cc;
      int flat = c * 512 + lane * 8;
      int row = flat >> 6, col = flat & 63;
      __builtin_amdgcn_global_load_lds(
          (const __attribute__((address_space(1))) void*)(Ap + (size_t)(m0 + row) * K + (k0 + col)),
          (__attribute__((address_space(3))) void*)&As[c * 512], 16, 0, 0);
    }
    // ---- B tile: fp32 -> bf16 reg staging, swizzled ----
#pragma unroll
    for (int it = 0; it < 4; ++it) {
      int flat = it * 2048 + t * 8;
      int row = flat >> 6, col = flat & 63;
      const float* g = Wp + (size_t)(n0 + row) * K + (k0 + col);
      float4 u0 = *(const float4*)g;
      float4 u1 = *(const float4*)(g + 4);
      uint4 v = {packbf2(u0.x, u0.y), packbf2(u0.z, u0.w),
                 packbf2(u1.x, u1.y), packbf2(u1.z, u1.w)};
      *(uint4*)&Bs[swz(flat)] = v;
    }
    __syncthreads();
#pragma unroll
    for (int kk = 0; kk < 2; ++kk) {
      bf16x8 a[4], b[4];
#pragma unroll
      for (int m = 0; m < 4; ++m)
        a[m] = *(const bf16x8*)&As[(wr * 64 + m * 16 + fr) * 64 + kk * 32 + fq * 8];
#pragma unroll
      for (int n = 0; n < 4; ++n)
        b[n] = *(const bf16x8*)&Bs[swz((wc * 64 + n * 16 + fr) * 64 + kk * 32 + fq * 8)];
#pragma unroll
      for (int m = 0; m < 4; ++m)
#pragma unroll
        for (int n = 0; n < 4; ++n)
          acc[m][n] = __builtin_amdgcn_mfma_f32_16x16x32_bf16(a[m], b[n], acc[m][n], 0, 0, 0);
    }
    __syncthreads();
  }

  // ---- epilogue ----
#pragma unroll
  for (int m = 0; m < 4; ++m)
#pragma unroll
    for (int n = 0; n < 4; ++n) {
      int row = m0 + wr * 64 + m * 16 + fq * 4;
      int col = n0 + wc * 64 + n * 16 + fr;
      if constexpr (OUT_MODE == 0) {
#pragma unroll
        for (int j = 0; j < 4; ++j)
          ((float*)Cp)[(size_t)(row + j) * N + col] = acc[m][n][j];
      } else if constexpr (OUT_MODE == 1) {
#pragma unroll
        for (int j = 0; j < 4; ++j)
          ((unsigned short*)Cp)[(size_t)(row + j) * N + col] = f2bf(acc[m][n][j]);
      } else {
        // V^T layout: (B, H, d_k=64, S=2048), s contiguous; 4 consecutive s/lane.
        int b = row >> 11, s = row & 2047;
        int h = col >> 6, d = col & 63;
        ushort4 v4 = {f2bf(acc[m][n][0]), f2bf(acc[m][n][1]),
                      f2bf(acc[m][n][2]), f2bf(acc[m][n][3])};
        *(ushort4*)&((unsigned short*)Cp)[(((size_t)b * 16 + h) * 64 + d) * 2048 + s] = v4;
      }
    }
}

// ---------------- RoPE (in-place, vectorized 4 pairs/thread) ----------------
// Q additionally scaled by 1/sqrt(d_k) = 0.125.
__global__ __launch_bounds__(256) void rope_kernel(unsigned short* __restrict__ Q,
                                                   unsigned short* __restrict__ Kb,
                                                   const int* __restrict__ tp) {
  int idx = blockIdx.x * 256 + threadIdx.x;     // uint4 index, 1M per matrix
  unsigned short* ptr = blockIdx.y ? Kb : Q;
  const float scale = blockIdx.y ? 1.0f : 0.125f;
  int flat8 = idx * 8;
  int r = flat8 >> 10;                 // row in (B*S)
  int colbase = flat8 & 1023;
  int ibase = (colbase & 63) >> 1;     // pair index within head
  int s = r & 2047;
  float pos = (float)tp[s];
  const float cexp = -13.287712379549449f / 32.0f;  // -log2(theta)/32

  uint4 v = *(const uint4*)&ptr[flat8];
  unsigned int* vp = (unsigned int*)&v;
  uint4 o;
  unsigned int* op = (unsigned int*)&o;
#pragma unroll
  for (int p = 0; p < 4; ++p) {
    float inv = exp2f((float)(ibase + p) * cexp);
    float ang = pos * inv;
    float sn, cs;
    sincosf(ang, &sn, &cs);
    float x1 = bf2f((unsigned short)(vp[p] & 0xFFFFu));
    float x2 = bf2f((unsigned short)(vp[p] >> 16));
    op[p] = packbf2((x1 * cs - x2 * sn) * scale, (x1 * sn + x2 * cs) * scale);
  }
  *(uint4*)&ptr[flat8] = o;
}

// ---------------- Flash attention, causal, paired q-tiles ----------------
// Block handles q-tile x then (31-x): 33 KV tiles total, uniform. 4 waves x 16 rows.
__global__ __launch_bounds__(256) void attn_kernel(const unsigned short* __restrict__ Q,
                                                   const unsigned short* __restrict__ K,
                                                   const unsigned short* __restrict__ Vt_g,
                                                   unsigned short* __restrict__ O) {
  __shared__ alignas(16) unsigned short Ks[64 * 64];
  __shared__ alignas(16) unsigned short Vt[64 * 64];   // [d][kv]
  __shared__ alignas(16) unsigned short Pl[4][16 * 64];
  const int t = threadIdx.x;
  const int lane = t & 63, w = t >> 6;
  const int fr = lane & 15, fq = lane >> 4;
  const int h = blockIdx.y, b = blockIdx.z;
  const size_t base = ((size_t)b * 2048) * 1024 + (size_t)h * 64;
  const size_t vbase = ((size_t)b * 16 + h) * 64 * 2048;
  const f32x4 zero = {0.f, 0.f, 0.f, 0.f};

  for (int pass = 0; pass < 2; ++pass) {
    const int qt = pass ? (31 - blockIdx.x) : blockIdx.x;
    const int q0 = qt * 64;

    // ---- stage Q tile through Ks (swizzled), hoist frags ----
    __syncthreads();  // prior pass's LDS readers done
#pragma unroll
    for (int it = 0; it < 2; ++it) {
      int flat = it * 2048 + t * 8;
      int row = flat >> 6, col = flat & 63;
      *(uint4*)&Ks[swz(flat)] = *(const uint4*)&Q[base + (size_t)(q0 + row) * 1024 + col];
    }
    __syncthreads();
    bf16x8 qf[2];
#pragma unroll
    for (int kk = 0; kk < 2; ++kk)
      qf[kk] = *(const bf16x8*)&Ks[swz((w * 16 + fr) * 64 + kk * 32 + fq * 8)];

    float m_[4] = {-INFINITY, -INFINITY, -INFINITY, -INFINITY};
    float l_[4] = {0.f, 0.f, 0.f, 0.f};
    f32x4 oacc[4];
#pragma unroll
    for (int n = 0; n < 4; ++n) oacc[n] = zero;

    // ---- T14 prefetch tile 0 ----
    uint4 kr[2], vr[2];
#pragma unroll
    for (int it = 0; it < 2; ++it) {
      int flat = it * 2048 + t * 8;
      int row = flat >> 6, col = flat & 63;
      kr[it] = *(const uint4*)&K[base + (size_t)(row) * 1024 + col];
      vr[it] = *(const uint4*)&Vt_g[vbase + (size_t)row * 2048 + col];
    }

    for (int kv0 = 0; kv0 <= q0; kv0 += 64) {
      __syncthreads();  // all waves done reading Ks/Vt
#pragma unroll
      for (int it = 0; it < 2; ++it) {
        int flat = it * 2048 + t * 8;
        *(uint4*)&Ks[swz(flat)] = kr[it];
        *(uint4*)&Vt[swz(flat)] = vr[it];
      }
      __syncthreads();
      // prefetch next tile (hidden under compute)
      if (kv0 + 64 <= q0) {
#pragma unroll
        for (int it = 0; it < 2; ++it) {
          int flat = it * 2048 + t * 8;
          int row = flat >> 6, col = flat & 63;
          kr[it] = *(const uint4*)&K[base + (size_t)(kv0 + 64 + row) * 1024 + col];
          vr[it] = *(const uint4*)&Vt_g[vbase + (size_t)row * 2048 + kv0 + 64 + col];
        }
      }

      // ---- S = Q K^T ----
      f32x4 sa[4];
#pragma unroll
      for (int n = 0; n < 4; ++n) sa[n] = zero;
#pragma unroll
      for (int kk = 0; kk < 2; ++kk) {
#pragma unroll
        for (int n = 0; n < 4; ++n) {
          bf16x8 kf = *(const bf16x8*)&Ks[swz((n * 16 + fr) * 64 + kk * 32 + fq * 8)];
          sa[n] = __builtin_amdgcn_mfma_f32_16x16x32_bf16(qf[kk], kf, sa[n], 0, 0, 0);
        }
      }

      // ---- online softmax (lane: rows fq*4+j, cols n*16+fr); Q pre-scaled ----
      const bool diag = (kv0 == q0);
      float sc[4][4], rmax[4];
#pragma unroll
      for (int j = 0; j < 4; ++j) rmax[j] = -3.0e38f;
#pragma unroll
      for (int n = 0; n < 4; ++n)
#pragma unroll
        for (int j = 0; j < 4; ++j) {
          float s = sa[n][j];
          if (diag && (n * 16 + fr > w * 16 + fq * 4 + j)) s = -3.0e38f;
          sc[n][j] = s;
          rmax[j] = fmaxf(rmax[j], s);
        }
#pragma unroll
      for (int msk = 1; msk < 16; msk <<= 1)
#pragma unroll
        for (int j = 0; j < 4; ++j) rmax[j] = fmaxf(rmax[j], __shfl_xor(rmax[j], msk));

      float alpha[4], psum[4];
#pragma unroll
      for (int j = 0; j < 4; ++j) {
        float mn = fmaxf(m_[j], rmax[j]);
        alpha[j] = exp2f((m_[j] - mn) * LOG2E);
        m_[j] = mn;
        psum[j] = 0.f;
      }
#pragma unroll
      for (int n = 0; n < 4; ++n)
#pragma unroll
        for (int j = 0; j < 4; ++j) {
          float p = exp2f((sc[n][j] - m_[j]) * LOG2E);
          psum[j] += p;
          Pl[w][swz((fq * 4 + j) * 64 + n * 16 + fr)] = f2bf(p);
        }
#pragma unroll
      for (int msk = 1; msk < 16; msk <<= 1)
#pragma unroll
        for (int j = 0; j < 4; ++j) psum[j] += __shfl_xor(psum[j], msk);
#pragma unroll
      for (int j = 0; j < 4; ++j) l_[j] = l_[j] * alpha[j] + psum[j];
#pragma unroll
      for (int n = 0; n < 4; ++n)
#pragma unroll
        for (int j = 0; j < 4; ++j) oacc[n][j] = oacc[n][j] * alpha[j];

      // ---- O += P V  (P: same-wave LDS round-trip, no barrier needed) ----
#pragma unroll
      for (int kk = 0; kk < 2; ++kk) {
        bf16x8 pf = *(const bf16x8*)&Pl[w][swz(fr * 64 + kk * 32 + fq * 8)];
#pragma unroll
        for (int n = 0; n < 4; ++n) {
          bf16x8 vf = *(const bf16x8*)&Vt[swz((n * 16 + fr) * 64 + kk * 32 + fq * 8)];
          oacc[n] = __builtin_amdgcn_mfma_f32_16x16x32_bf16(pf, vf, oacc[n], 0, 0, 0);
        }
      }
    }

    // ---- epilogue ----
    float rl[4];
#pragma unroll
    for (int j = 0; j < 4; ++j) rl[j] = 1.0f / l_[j];
#pragma unroll
    for (int n = 0; n < 4; ++n)
#pragma unroll
      for (int j = 0; j < 4; ++j) {
        float o = oacc[n][j] * rl[j];
        size_t row = (size_t)(q0 + w * 16 + fq * 4 + j);
        O[base + row * 1024 + n * 16 + fr] = f2bf(o);
      }
  }
}

extern "C" void kernel_launch(void* const* d_in, const int* in_sizes, int n_in,
                              void* d_out, int out_size, void* d_ws, size_t ws_size,
                              hipStream_t stream) {
  const float* x  = (const float*)d_in[0];
  const int* tp   = (const int*)d_in[1];
  const float* Wq = (const float*)d_in[2];
  const float* Wk = (const float*)d_in[3];
  const float* Wv = (const float*)d_in[4];
  const float* Wo = (const float*)d_in[5];
  float* out = (float*)d_out;

  const size_t MAT = (size_t)8192 * 1024;  // elements per bf16 matrix
  unsigned short* Qb  = (unsigned short*)d_ws;
  unsigned short* Kb  = Qb + MAT;
  unsigned short* Vtb = Kb + MAT;          // V^T (B,H,64,2048)
  unsigned short* Xb  = Vtb + MAT;         // x as bf16; later reused as Ob
  unsigned short* Ob  = Xb;                // attn output overwrites Xb (dead by then)

  cvt_kernel<<<4096, 256, 0, stream>>>(x, Xb, 8192 * 1024 / 8);
  dim3 gg(64, 8);  // M/128, N/128
  gemm_bt<1><<<gg, 256, 0, stream>>>(Xb, Wq, (void*)Qb, 8192, 1024, 1024);
  gemm_bt<1><<<gg, 256, 0, stream>>>(Xb, Wk, (void*)Kb, 8192, 1024, 1024);
  gemm_bt<2><<<gg, 256, 0, stream>>>(Xb, Wv, (void*)Vtb, 8192, 1024, 1024);
  rope_kernel<<<dim3(4096, 2), 256, 0, stream>>>(Qb, Kb, tp);
  attn_kernel<<<dim3(16, 16, 4), 256, 0, stream>>>(Qb, Kb, Vtb, Ob);
  gemm_bt<0><<<gg, 256, 0, stream>>>(Ob, Wo, (void*)out, 8192, 1024, 1024);
}

// Round 5
// 409.688 us; speedup vs baseline: 1.7619x; 1.1187x over previous
//
#include <hip/hip_runtime.h>
#include <cstdint>
#include <cstddef>

// MultiHeadSelfAttention forward, MI355X/gfx950.  Round 4 (resubmit after infra failure).
//  - gemm_qkv: one fused GEMM (N=3072) for Q,K,V; A (x) and B (W, pre-converted
//    bf16 into d_out scratch) both staged via global_load_lds width-16 (m97).
//  - attn: swapped-QK^T structure. S^T = mfma(K,Q) puts a full S-row per lane
//    (q = lane&15); softmax reduction = in-lane + 2 shfl. P redistributed to
//    PV B-frag layout by an in-register 4x4 butterfly transpose across fq
//    groups (8 shfl_xor). O^T = mfma(V^T, P^T). No P LDS buffer.
//
// Frag layouts (verified, mfma_f32_16x16x32_bf16):
//   C/D: row = (lane>>4)*4 + j, col = lane&15
//   A:   row = lane&15,        k = (lane>>4)*8 + j
//   B:   col = lane&15,        k = (lane>>4)*8 + j

typedef __attribute__((ext_vector_type(8))) short bf16x8;
typedef __attribute__((ext_vector_type(4))) float f32x4;

#define LOG2E 1.4426950408889634f

__device__ __forceinline__ unsigned short f2bf(float f) {
  unsigned int u = __builtin_bit_cast(unsigned int, f);
  unsigned int r = (u + 0x7FFFu + ((u >> 16) & 1u)) >> 16;  // RNE
  return (unsigned short)r;
}
__device__ __forceinline__ float bf2f(unsigned short h) {
  return __builtin_bit_cast(float, (unsigned int)h << 16);
}
__device__ __forceinline__ unsigned int packbf2(float a, float b) {
  return (unsigned int)f2bf(a) | ((unsigned int)f2bf(b) << 16);
}
// XOR swizzle for [R][64]-ushort row-major LDS tiles: byte ^= ((row&7)<<4).
__device__ __forceinline__ int swz(int idx) {
  return idx ^ (((idx >> 6) & 7) << 3);
}

// ---------------- fp32 -> bf16 bulk converts ----------------
__global__ __launch_bounds__(256) void cvt_kernel(const float* __restrict__ in,
                                                  unsigned short* __restrict__ out,
                                                  int n8) {
  int i = blockIdx.x * 256 + threadIdx.x;
  if (i < n8) {
    float4 u0 = ((const float4*)in)[i * 2];
    float4 u1 = ((const float4*)in)[i * 2 + 1];
    uint4 v = {packbf2(u0.x, u0.y), packbf2(u0.z, u0.w),
               packbf2(u1.x, u1.y), packbf2(u1.z, u1.w)};
    ((uint4*)out)[i] = v;
  }
}
// Convert Wq/Wk/Wv (1M fp32 each) -> bf16, dst selected by blockIdx.y.
__global__ __launch_bounds__(256) void cvt_w3(const float* __restrict__ w0,
                                              const float* __restrict__ w1,
                                              const float* __restrict__ w2,
                                              unsigned short* __restrict__ dst) {
  const float* src = blockIdx.y == 0 ? w0 : (blockIdx.y == 1 ? w1 : w2);
  unsigned short* d = dst + (size_t)blockIdx.y * 1024 * 1024;
  int i = blockIdx.x * 256 + threadIdx.x;  // 131072 uint4 groups
  float4 u0 = ((const float4*)src)[i * 2];
  float4 u1 = ((const float4*)src)[i * 2 + 1];
  uint4 v = {packbf2(u0.x, u0.y), packbf2(u0.z, u0.w),
             packbf2(u1.x, u1.y), packbf2(u1.z, u1.w)};
  ((uint4*)d)[i] = v;
}

// ---------------- fused QKV GEMM ----------------
// C = Xb[8192,1024](bf16) * W[3072,1024]^T(bf16). 128x128 tile, BK=64, 4 waves.
// Both operands via global_load_lds (linear LDS, m97 structure).
// by in [0,24): sel = by>>3 chooses Q/K/V output; V written transposed.
__global__ __launch_bounds__(256) void gemm_qkv(const unsigned short* __restrict__ Xb,
                                                const unsigned short* __restrict__ Wb3,
                                                unsigned short* __restrict__ Qb,
                                                unsigned short* __restrict__ Kb,
                                                unsigned short* __restrict__ Vtb) {
  __shared__ alignas(16) unsigned short As[128 * 64];
  __shared__ alignas(16) unsigned short Bs[128 * 64];
  const int t = threadIdx.x;
  const int lane = t & 63;
  const int w = t >> 6;
  const int wr = w >> 1, wc = w & 1;
  const int fr = lane & 15, fq = lane >> 4;
  const int m0 = blockIdx.x * 128;
  const int sel = blockIdx.y >> 3;
  const int n0 = (blockIdx.y & 7) * 128;  // col within 1024
  const unsigned short* Wp = Wb3 + (size_t)sel * 1024 * 1024;
  const int K = 1024;

  const f32x4 zero = {0.f, 0.f, 0.f, 0.f};
  f32x4 acc[4][4];
#pragma unroll
  for (int m = 0; m < 4; ++m)
#pragma unroll
    for (int n = 0; n < 4; ++n) acc[m][n] = zero;

  for (int k0 = 0; k0 < K; k0 += 64) {
#pragma unroll
    for (int cc = 0; cc < 4; ++cc) {
      int c = w * 4 + cc;
      int flat = c * 512 + lane * 8;
      int row = flat >> 6, col = flat & 63;
      __builtin_amdgcn_global_load_lds(
          (const __attribute__((address_space(1))) void*)(Xb + (size_t)(m0 + row) * K + (k0 + col)),
          (__attribute__((address_space(3))) void*)&As[c * 512], 16, 0, 0);
      __builtin_amdgcn_global_load_lds(
          (const __attribute__((address_space(1))) void*)(Wp + (size_t)(n0 + row) * K + (k0 + col)),
          (__attribute__((address_space(3))) void*)&Bs[c * 512], 16, 0, 0);
    }
    __syncthreads();
#pragma unroll
    for (int kk = 0; kk < 2; ++kk) {
      bf16x8 a[4], b[4];
#pragma unroll
      for (int m = 0; m < 4; ++m)
        a[m] = *(const bf16x8*)&As[(wr * 64 + m * 16 + fr) * 64 + kk * 32 + fq * 8];
#pragma unroll
      for (int n = 0; n < 4; ++n)
        b[n] = *(const bf16x8*)&Bs[(wc * 64 + n * 16 + fr) * 64 + kk * 32 + fq * 8];
#pragma unroll
      for (int m = 0; m < 4; ++m)
#pragma unroll
        for (int n = 0; n < 4; ++n)
          acc[m][n] = __builtin_amdgcn_mfma_f32_16x16x32_bf16(a[m], b[n], acc[m][n], 0, 0, 0);
    }
    __syncthreads();
  }

#pragma unroll
  for (int m = 0; m < 4; ++m)
#pragma unroll
    for (int n = 0; n < 4; ++n) {
      int row = m0 + wr * 64 + m * 16 + fq * 4;
      int col = n0 + wc * 64 + n * 16 + fr;
      if (sel < 2) {
        unsigned short* Cp = sel ? Kb : Qb;
#pragma unroll
        for (int j = 0; j < 4; ++j)
          Cp[(size_t)(row + j) * 1024 + col] = f2bf(acc[m][n][j]);
      } else {
        // V^T layout: (B, H, d_k=64, S=2048), s contiguous; 4 consecutive s/lane.
        int b = row >> 11, s = row & 2047;
        int h = col >> 6, d = col & 63;
        ushort4 v4 = {f2bf(acc[m][n][0]), f2bf(acc[m][n][1]),
                      f2bf(acc[m][n][2]), f2bf(acc[m][n][3])};
        *(ushort4*)&Vtb[(((size_t)b * 16 + h) * 64 + d) * 2048 + s] = v4;
      }
    }
}

// ---------------- RoPE (in-place, 4 pairs/thread) ----------------
// Q additionally scaled by (1/sqrt(d_k))*log2(e) so attn can use exp2 directly.
__global__ __launch_bounds__(256) void rope_kernel(unsigned short* __restrict__ Q,
                                                   unsigned short* __restrict__ Kb,
                                                   const int* __restrict__ tp) {
  int idx = blockIdx.x * 256 + threadIdx.x;
  unsigned short* ptr = blockIdx.y ? Kb : Q;
  const float scale = blockIdx.y ? 1.0f : 0.125f * LOG2E;
  int flat8 = idx * 8;
  int r = flat8 >> 10;
  int colbase = flat8 & 1023;
  int ibase = (colbase & 63) >> 1;
  int s = r & 2047;
  float pos = (float)tp[s];
  const float cexp = -13.287712379549449f / 32.0f;  // -log2(theta)/32

  uint4 v = *(const uint4*)&ptr[flat8];
  unsigned int* vp = (unsigned int*)&v;
  uint4 o;
  unsigned int* op = (unsigned int*)&o;
#pragma unroll
  for (int p = 0; p < 4; ++p) {
    float inv = exp2f((float)(ibase + p) * cexp);
    float ang = pos * inv;
    float sn, cs;
    sincosf(ang, &sn, &cs);
    float x1 = bf2f((unsigned short)(vp[p] & 0xFFFFu));
    float x2 = bf2f((unsigned short)(vp[p] >> 16));
    op[p] = packbf2((x1 * cs - x2 * sn) * scale, (x1 * sn + x2 * cs) * scale);
  }
  *(uint4*)&ptr[flat8] = o;
}

// ---------------- Flash attention, causal, swapped QK^T ----------------
// Block: (b, h, paired q-tiles x and 31-x). 4 waves x 16 q-rows.
// Lane (fr,fq) owns q-row w*16+fr; S^T gives it kv = n*16+fq*4+j (16 values).
__global__ __launch_bounds__(256) void attn_kernel(const unsigned short* __restrict__ Q,
                                                   const unsigned short* __restrict__ K,
                                                   const unsigned short* __restrict__ Vt_g,
                                                   unsigned short* __restrict__ O) {
  __shared__ alignas(16) unsigned short Ks[64 * 64];
  __shared__ alignas(16) unsigned short Vt[64 * 64];   // [d][kv]
  const int t = threadIdx.x;
  const int lane = t & 63, w = t >> 6;
  const int fr = lane & 15, fq = lane >> 4;
  const int h = blockIdx.y, b = blockIdx.z;
  const size_t base = ((size_t)b * 2048) * 1024 + (size_t)h * 64;
  const size_t vbase = ((size_t)b * 16 + h) * 64 * 2048;
  const f32x4 zero = {0.f, 0.f, 0.f, 0.f};

  for (int pass = 0; pass < 2; ++pass) {
    const int qt = pass ? (31 - blockIdx.x) : blockIdx.x;
    const int q0 = qt * 64;

    // Q frags straight from global (row = q0 + w*16 + fr, 16B contiguous).
    bf16x8 qf[2];
#pragma unroll
    for (int kk = 0; kk < 2; ++kk)
      qf[kk] = *(const bf16x8*)&Q[base + (size_t)(q0 + w * 16 + fr) * 1024 + kk * 32 + fq * 8];

    float m_ = -INFINITY, l_ = 0.f;
    f32x4 oaccT[4];
#pragma unroll
    for (int n = 0; n < 4; ++n) oaccT[n] = zero;

    // prefetch tile 0
    uint4 kr[2], vr[2];
#pragma unroll
    for (int it = 0; it < 2; ++it) {
      int flat = it * 2048 + t * 8;
      int row = flat >> 6, col = flat & 63;
      kr[it] = *(const uint4*)&K[base + (size_t)row * 1024 + col];
      vr[it] = *(const uint4*)&Vt_g[vbase + (size_t)row * 2048 + col];
    }

    for (int kv0 = 0; kv0 <= q0; kv0 += 64) {
      __syncthreads();
#pragma unroll
      for (int it = 0; it < 2; ++it) {
        int flat = it * 2048 + t * 8;
        *(uint4*)&Ks[swz(flat)] = kr[it];
        *(uint4*)&Vt[swz(flat)] = vr[it];
      }
      __syncthreads();
      if (kv0 + 64 <= q0) {
#pragma unroll
        for (int it = 0; it < 2; ++it) {
          int flat = it * 2048 + t * 8;
          int row = flat >> 6, col = flat & 63;
          kr[it] = *(const uint4*)&K[base + (size_t)(kv0 + 64 + row) * 1024 + col];
          vr[it] = *(const uint4*)&Vt_g[vbase + (size_t)row * 2048 + kv0 + 64 + col];
        }
      }

      // ---- S^T = K Q^T : lane holds S[kv = n*16+fq*4+j][q = w*16+fr] ----
      f32x4 sa[4];
#pragma unroll
      for (int n = 0; n < 4; ++n) sa[n] = zero;
#pragma unroll
      for (int kk = 0; kk < 2; ++kk) {
#pragma unroll
        for (int n = 0; n < 4; ++n) {
          bf16x8 kf = *(const bf16x8*)&Ks[swz((n * 16 + fr) * 64 + kk * 32 + fq * 8)];
          sa[n] = __builtin_amdgcn_mfma_f32_16x16x32_bf16(kf, qf[kk], sa[n], 0, 0, 0);
        }
      }

      // ---- softmax (scores already in log2 units; row local to lane) ----
      const bool diag = (kv0 == q0);
      float pmax = -3.0e38f;
#pragma unroll
      for (int n = 0; n < 4; ++n)
#pragma unroll
        for (int j = 0; j < 4; ++j) {
          float s = sa[n][j];
          if (diag && (n * 16 + fq * 4 + j > w * 16 + fr)) s = -3.0e38f;
          sa[n][j] = s;
          pmax = fmaxf(pmax, s);
        }
      pmax = fmaxf(pmax, __shfl_xor(pmax, 16));
      pmax = fmaxf(pmax, __shfl_xor(pmax, 32));
      float mn = fmaxf(m_, pmax);
      float alpha = exp2f(m_ - mn);
      m_ = mn;
      float ps = 0.f;
#pragma unroll
      for (int n = 0; n < 4; ++n)
#pragma unroll
        for (int j = 0; j < 4; ++j) {
          float e = exp2f(sa[n][j] - mn);
          sa[n][j] = e;
          ps += e;
        }
      ps += __shfl_xor(ps, 16);
      ps += __shfl_xor(ps, 32);
      l_ = l_ * alpha + ps;
#pragma unroll
      for (int n = 0; n < 4; ++n)
#pragma unroll
        for (int j = 0; j < 4; ++j) oaccT[n][j] *= alpha;

      // ---- P^T -> PV B-frag: in-register 4x4 butterfly across fq groups ----
      // Pair index P = kv>>1 = n*8 + fq*2 + pp (held) ; need P = kk*16 + fq*4 + r.
      // Step1 (xor32) then Step2 (xor16); verified mapping (hand-simulated all fq):
      unsigned R[4][2], F[4][2];
#pragma unroll
      for (int n = 0; n < 4; ++n)
#pragma unroll
        for (int pp = 0; pp < 2; ++pp)
          R[n][pp] = packbf2(sa[n][2 * pp], sa[n][2 * pp + 1]);
#pragma unroll
      for (int pp = 0; pp < 2; ++pp) {
        unsigned t0 = (fq < 2) ? R[1][pp] : R[0][pp];
        unsigned t1 = (fq < 2) ? R[3][pp] : R[2][pp];
        t0 = (unsigned)__shfl_xor((int)t0, 32);
        t1 = (unsigned)__shfl_xor((int)t1, 32);
        unsigned G0 = (fq < 2) ? R[0][pp] : t0;
        unsigned G1 = (fq < 2) ? t0 : R[1][pp];
        unsigned G2 = (fq < 2) ? R[2][pp] : t1;
        unsigned G3 = (fq < 2) ? t1 : R[3][pp];
        unsigned u0 = ((fq & 1) == 0) ? G1 : G0;
        unsigned u1 = ((fq & 1) == 0) ? G3 : G2;
        u0 = (unsigned)__shfl_xor((int)u0, 16);
        u1 = (unsigned)__shfl_xor((int)u1, 16);
        F[0][pp] = ((fq & 1) == 0) ? G0 : u0;
        F[1][pp] = ((fq & 1) == 0) ? u0 : G1;
        F[2][pp] = ((fq & 1) == 0) ? G2 : u1;
        F[3][pp] = ((fq & 1) == 0) ? u1 : G3;
      }
      union U8 { unsigned u[4]; bf16x8 v; };
      U8 pb0, pb1;
      pb0.u[0] = F[0][0]; pb0.u[1] = F[0][1]; pb0.u[2] = F[1][0]; pb0.u[3] = F[1][1];
      pb1.u[0] = F[2][0]; pb1.u[1] = F[2][1]; pb1.u[2] = F[3][0]; pb1.u[3] = F[3][1];

      // ---- O^T += V^T P^T : oaccT[n] rows d=n*16+fq*4+j, col q=fr ----
#pragma unroll
      for (int n = 0; n < 4; ++n) {
        bf16x8 vf0 = *(const bf16x8*)&Vt[swz((n * 16 + fr) * 64 + 0 * 32 + fq * 8)];
        oaccT[n] = __builtin_amdgcn_mfma_f32_16x16x32_bf16(vf0, pb0.v, oaccT[n], 0, 0, 0);
        bf16x8 vf1 = *(const bf16x8*)&Vt[swz((n * 16 + fr) * 64 + 1 * 32 + fq * 8)];
        oaccT[n] = __builtin_amdgcn_mfma_f32_16x16x32_bf16(vf1, pb1.v, oaccT[n], 0, 0, 0);
      }
    }

    // ---- epilogue: O[q][d], lane's q = q0+w*16+fr, d = n*16+fq*4+(0..3) ----
    float rl = 1.0f / l_;
#pragma unroll
    for (int n = 0; n < 4; ++n) {
      ushort4 v4 = {f2bf(oaccT[n][0] * rl), f2bf(oaccT[n][1] * rl),
                    f2bf(oaccT[n][2] * rl), f2bf(oaccT[n][3] * rl)};
      *(ushort4*)&O[base + (size_t)(q0 + w * 16 + fr) * 1024 + n * 16 + fq * 4] = v4;
    }
  }
}

// ---------------- out GEMM: C fp32 = A(bf16) * W(fp32)^T ----------------
__global__ __launch_bounds__(256) void gemm_out(const unsigned short* __restrict__ Ap,
                                                const float* __restrict__ Wp,
                                                float* __restrict__ Cp) {
  __shared__ alignas(16) unsigned short As[128 * 64];
  __shared__ alignas(16) unsigned short Bs[128 * 64];
  const int t = threadIdx.x;
  const int lane = t & 63;
  const int w = t >> 6;
  const int wr = w >> 1, wc = w & 1;
  const int fr = lane & 15, fq = lane >> 4;
  const int m0 = blockIdx.x * 128, n0 = blockIdx.y * 128;
  const int K = 1024, N = 1024;

  const f32x4 zero = {0.f, 0.f, 0.f, 0.f};
  f32x4 acc[4][4];
#pragma unroll
  for (int m = 0; m < 4; ++m)
#pragma unroll
    for (int n = 0; n < 4; ++n) acc[m][n] = zero;

  for (int k0 = 0; k0 < K; k0 += 64) {
#pragma unroll
    for (int cc = 0; cc < 4; ++cc) {
      int c = w * 4 + cc;
      int flat = c * 512 + lane * 8;
      int row = flat >> 6, col = flat & 63;
      __builtin_amdgcn_global_load_lds(
          (const __attribute__((address_space(1))) void*)(Ap + (size_t)(m0 + row) * K + (k0 + col)),
          (__attribute__((address_space(3))) void*)&As[c * 512], 16, 0, 0);
    }
#pragma unroll
    for (int it = 0; it < 4; ++it) {
      int flat = it * 2048 + t * 8;
      int row = flat >> 6, col = flat & 63;
      const float* g = Wp + (size_t)(n0 + row) * K + (k0 + col);
      float4 u0 = *(const float4*)g;
      float4 u1 = *(const float4*)(g + 4);
      uint4 v = {packbf2(u0.x, u0.y), packbf2(u0.z, u0.w),
                 packbf2(u1.x, u1.y), packbf2(u1.z, u1.w)};
      *(uint4*)&Bs[swz(flat)] = v;
    }
    __syncthreads();
#pragma unroll
    for (int kk = 0; kk < 2; ++kk) {
      bf16x8 a[4], b[4];
#pragma unroll
      for (int m = 0; m < 4; ++m)
        a[m] = *(const bf16x8*)&As[(wr * 64 + m * 16 + fr) * 64 + kk * 32 + fq * 8];
#pragma unroll
      for (int n = 0; n < 4; ++n)
        b[n] = *(const bf16x8*)&Bs[swz((wc * 64 + n * 16 + fr) * 64 + kk * 32 + fq * 8)];
#pragma unroll
      for (int m = 0; m < 4; ++m)
#pragma unroll
        for (int n = 0; n < 4; ++n)
          acc[m][n] = __builtin_amdgcn_mfma_f32_16x16x32_bf16(a[m], b[n], acc[m][n], 0, 0, 0);
    }
    __syncthreads();
  }

#pragma unroll
  for (int m = 0; m < 4; ++m)
#pragma unroll
    for (int n = 0; n < 4; ++n) {
      int row = m0 + wr * 64 + m * 16 + fq * 4;
      int col = n0 + wc * 64 + n * 16 + fr;
#pragma unroll
      for (int j = 0; j < 4; ++j)
        Cp[(size_t)(row + j) * N + col] = acc[m][n][j];
    }
}

extern "C" void kernel_launch(void* const* d_in, const int* in_sizes, int n_in,
                              void* d_out, int out_size, void* d_ws, size_t ws_size,
                              hipStream_t stream) {
  const float* x  = (const float*)d_in[0];
  const int* tp   = (const int*)d_in[1];
  const float* Wq = (const float*)d_in[2];
  const float* Wk = (const float*)d_in[3];
  const float* Wv = (const float*)d_in[4];
  const float* Wo = (const float*)d_in[5];
  float* out = (float*)d_out;

  const size_t MAT = (size_t)8192 * 1024;
  unsigned short* Qb  = (unsigned short*)d_ws;
  unsigned short* Kb  = Qb + MAT;
  unsigned short* Vtb = Kb + MAT;          // V^T (B,H,64,2048)
  unsigned short* Xb  = Vtb + MAT;         // x bf16; reused as Ob after gemm_qkv
  unsigned short* Ob  = Xb;
  unsigned short* Wb3 = (unsigned short*)d_out;  // Wq/Wk/Wv bf16 scratch (6 MB of 32 MB)

  cvt_kernel<<<4096, 256, 0, stream>>>(x, Xb, 8192 * 1024 / 8);
  cvt_w3<<<dim3(512, 3), 256, 0, stream>>>(Wq, Wk, Wv, Wb3);
  gemm_qkv<<<dim3(64, 24), 256, 0, stream>>>(Xb, Wb3, Qb, Kb, Vtb);
  rope_kernel<<<dim3(4096, 2), 256, 0, stream>>>(Qb, Kb, tp);
  attn_kernel<<<dim3(16, 16, 4), 256, 0, stream>>>(Qb, Kb, Vtb, Ob);
  gemm_out<<<dim3(64, 8), 256, 0, stream>>>(Ob, Wo, out);
}